// Round 3
// baseline (3453.999 us; speedup 1.0000x reference)
//
#include <hip/hip_runtime.h>
#include <cstdint>
#include <cstddef>

// Problem constants (match reference)
#define NIT    500
#define GAMMA_ 5.0f
#define CC_    1e-3f
#define KAPPA_ 2.0627128075074256f
#define PEN_   100.0f
#define LR_    0.01f

// r18 d_ws layout: pbuf [128 b][3 boundary][2 dir][100] f32 = 307200 B (single slot
// per direction + ack handshake), then flags[768] + acks[768] ints = 6144 B.
// TOTAL ~313 KB <= 410 KB proven-safe budget (r6/r14: 617 KB layouts failed).
#define PBUF_BYTES (128*6*100*4)
#define FLAG_COUNT 1536   // [0..767] flags, [768..1535] acks

// Cross-WG primitives (r11/r13-proven): relaxed SYSTEM-scope atomic load/store ->
// coherence point, no cache-wide maintenance (r11: agent acq/rel wb/inv was a
// ~6us/iter floor), no RMW serialization (r12: RMW polls = HBM atomic storm).
#define VMFENCE() asm volatile("s_waitcnt vmcnt(0)" ::: "memory")
__device__ __forceinline__ float sysLoadF(float* p) {
  return __hip_atomic_load(p, __ATOMIC_RELAXED, __HIP_MEMORY_SCOPE_SYSTEM);
}
__device__ __forceinline__ void sysStoreF(float* p, float v) {
  __hip_atomic_store(p, v, __ATOMIC_RELAXED, __HIP_MEMORY_SCOPE_SYSTEM);
}
__device__ __forceinline__ int sysLoadI(int* p) {
  return __hip_atomic_load(p, __ATOMIC_RELAXED, __HIP_MEMORY_SCOPE_SYSTEM);
}
__device__ __forceinline__ void sysStoreI(int* p, int v) {
  __hip_atomic_store(p, v, __ATOMIC_RELAXED, __HIP_MEMORY_SCOPE_SYSTEM);
}
__device__ __forceinline__ int flagRead(int* p, int lane) {
  int f = 0;
  if (lane == 0) f = sysLoadI(p);
  return __builtin_amdgcn_readfirstlane(f);
}
// Intra-WG flag in LDS: workgroup-scope acq/rel = lgkm waits only, no cache ops.
__device__ __forceinline__ int ldsLoadAcq(int* p) {
  return __hip_atomic_load(p, __ATOMIC_ACQUIRE, __HIP_MEMORY_SCOPE_WORKGROUP);
}
__device__ __forceinline__ void ldsStoreRel(int* p, int v) {
  __hip_atomic_store(p, v, __ATOMIC_RELEASE, __HIP_MEMORY_SCOPE_WORKGROUP);
}

__device__ __forceinline__ float rdlane(float v, int lane) {
  return __int_as_float(__builtin_amdgcn_readlane(__float_as_int(v), lane));
}

// Wave64 sum via DPP, total broadcast from lane 63. Verified r5..r13.
__device__ __forceinline__ float wred64(float x) {
  int t;
  t = __builtin_amdgcn_update_dpp(0, __float_as_int(x), 0x111, 0xf, 0xf, true); x += __int_as_float(t);
  t = __builtin_amdgcn_update_dpp(0, __float_as_int(x), 0x112, 0xf, 0xf, true); x += __int_as_float(t);
  t = __builtin_amdgcn_update_dpp(0, __float_as_int(x), 0x114, 0xf, 0xf, true); x += __int_as_float(t);
  t = __builtin_amdgcn_update_dpp(0, __float_as_int(x), 0x118, 0xf, 0xf, true); x += __int_as_float(t);
  t = __builtin_amdgcn_update_dpp(0, __float_as_int(x), 0x142, 0xa, 0xf, true); x += __int_as_float(t);
  t = __builtin_amdgcn_update_dpp(0, __float_as_int(x), 0x143, 0xc, 0xf, true); x += __int_as_float(t);
  return rdlane(x, 63);
}

#define SPIN_LDS(PTR, TGT)                                                   \
  do {                                                                       \
    if (!dead) {                                                             \
      long guard_ = 0;                                                       \
      while (ldsLoadAcq(PTR) < (TGT)) {                                      \
        __builtin_amdgcn_s_sleep(1);                                         \
        if (++guard_ > (1L << 18)) { dead = true; break; }                   \
      }                                                                      \
    }                                                                        \
  } while (0)

#define SPIN_SYS(PTR, TGT)                                                   \
  do {                                                                       \
    if (!dead) {                                                             \
      long guard_ = 0;                                                       \
      while (flagRead((PTR), lane) < (TGT)) {                                \
        __builtin_amdgcn_s_sleep(1);                                         \
        if (++guard_ > (1L << 18)) { dead = true; break; }                   \
      }                                                                      \
    }                                                                        \
  } while (0)

// r18: TWO INDEPENDENT DEPENDENCY DOMAINS PER CU.
// r15=1651us, r16 (flag desync, same 1 domain/CU)=1714, r17 (SIMD remap)=1698:
// ~60% of cycles are latency stalls (cross-WG LLC round-trips + serial DPP chains)
// that nothing on the CU can hide because all 12 waves share one barrier/dep web.
// Fix: 384-thread WGs (3 heads x 2 waves), grid 512 = (b, quarter). Breadth-first
// dispatch co-locates bids i and i+256 -> with bid=b*4+q the co-resident WG is a
// DIFFERENT batch (b+-64): its compute fills our stalls. bid=b*4+q also keeps all
// 4 quarters of a batch in one dispatch round -> no residency deadlock.
// Cross-WG now at 3 boundaries/batch (heads 2|3, 5|6, 8|9). ws budget forces
// single-slot pbuf + ACK handshake: producer overwrites w^k only after consumer
// acked reading it (consumer: loads -> vmcnt drain -> ack; bounded skew 1, no cycle).
// Neighbor values remain EXACTLY w^k (Jacobi preserved) -> arithmetic bitwise
// identical to r15 -> absmax must stay 0.0001220703.
// S constant-indexed only (r9: runtime index -> scratch spill -> 19.6 GB FETCH).
__global__ __launch_bounds__(384, 1) void mpo_solver(
    const float* __restrict__ mu, const float* __restrict__ L,
    const float* __restrict__ wprev, const float* __restrict__ climit,
    float* __restrict__ out, float* __restrict__ pbuf, int* __restrict__ flags)
{
  const int tid  = threadIdx.x;
  const int lane = tid & 63;
  const int wave = __builtin_amdgcn_readfirstlane(tid >> 6);  // 0..5
  const int j    = wave >> 1;       // local head 0..2
  const int sec  = wave & 1;        // 0 = A (rows 0-49 + post), 1 = B (rows 50-99)
  const int bid  = blockIdx.x;
  const int b    = bid >> 2;
  const int q    = bid & 3;         // quarter: heads 3q..3q+2
  const int h    = q * 3 + j;       // global head
  const int bh   = b * 12 + h;
  int* acks = flags + 768;

  __shared__ float wbuf[2][3][100];   // double-buffered w per head
  __shared__ float ybuf[3][100];      // y rows 50-99 per head (B-wave's half)
  __shared__ float nbufL[100];        // cross-WG left-neighbor w (head 3q-1)
  __shared__ float nbufR[100];        // cross-WG right-neighbor w (head 3q+3)
  __shared__ int   nflagL, nflagR;    // nbuf holds iter-k data -> k

  const float* Lb = L + (size_t)bh * 10000;

  // ---------- Phase 0: SYRK. Lane owns row r of S = L L^T (fp32 regs/AGPRs). ----------
  float S[100];
#pragma unroll
  for (int c = 0; c < 100; ++c) S[c] = 0.f;
  const int r = sec * 50 + lane;      // valid row iff lane < 50
  if (lane < 50) {
#pragma unroll 1
    for (int mc = 0; mc < 25; ++mc) {
      float4 lr = *(const float4*)(Lb + r * 100 + mc * 4);
#pragma unroll
      for (int c = 0; c < 100; ++c) {
        const float* Lc = Lb + c * 100 + mc * 4;   // wave-uniform -> scalar loads
        S[c] = fmaf(lr.x, Lc[0], fmaf(lr.y, Lc[1], fmaf(lr.z, Lc[2], fmaf(lr.w, Lc[3], S[c]))));
      }
    }
  }

  const bool val1 = (lane < 36);
  float mu0 = mu[(size_t)bh * 100 + lane];
  float mu1 = val1 ? mu[(size_t)bh * 100 + 64 + lane] : 0.f;
  float wp0 = wprev[b * 100 + lane];
  float wp1 = val1 ? wprev[b * 100 + 64 + lane] : 0.f;
  float lim = climit[b];

  float w0 = wp0, w1 = wp1;           // post wave's iterate (n = lane, 64+lane)

  if (sec == 0) {
    wbuf[0][j][lane] = wp0;
    if (val1) wbuf[0][j][64 + lane] = wp1;
  }
  if (tid == 0) { nflagL = 0; nflagR = 0; }
  __syncthreads();

  const bool hasNext = (h < 11);
  // Boundary m separates heads 3m+2 / 3m+3. dir id = b*6 + m*2 + {0:R->, 1:<-L}.
  const bool conL = (j == 0) && (q > 0);   // consumes head 3q-1 via dirR(q-1); also publishes dirL(q-1)
  const bool conR = (j == 2) && (q < 3);   // consumes head 3q+3 via dirL(q);   also publishes dirR(q)
  const bool isBnd = conL || conR;
  const int  dirConsume = conL ? (b * 6 + (q - 1) * 2 + 0) : (b * 6 + q * 2 + 1);
  const int  dirPublish = conL ? (b * 6 + (q - 1) * 2 + 1) : (b * 6 + q * 2 + 0);
  bool dead = false;
  float thp = -3.0e38f;               // warm Michelot seed; k=0 -> full support

  for (int k = 0; k < NIT; ++k) {
    const int p = k & 1;

    // ---------- matvec y = S * w_k: wave-uniform ds_read_b128 broadcast ----------
    float yloc;
    {
      float a0 = 0.f, a1 = 0.f, a2 = 0.f, a3 = 0.f;
      const float* wrow = wbuf[p][j];
#pragma unroll
      for (int qq = 0; qq < 25; ++qq) {
        float4 wq = *(const float4*)(wrow + qq * 4);
        a0 = fmaf(wq.x, S[qq * 4 + 0], a0);
        a1 = fmaf(wq.y, S[qq * 4 + 1], a1);
        a2 = fmaf(wq.z, S[qq * 4 + 2], a2);
        a3 = fmaf(wq.w, S[qq * 4 + 3], a3);
      }
      yloc = (a0 + a2) + (a1 + a3);
      if (sec == 1 && lane < 50) ybuf[j][50 + lane] = yloc;  // only B publishes its half
    }
    __syncthreads();

    // ================= post window =================
    if (sec == 1) {
      // ---- B wave of a boundary head: delegated cross-WG read (otherwise idle) ----
      if (isBnd && k > 0) {
        SPIN_SYS(&flags[dirConsume], k);
        // two-phase: data issued only after flag>=k observed (producer fenced
        // data before flag -> flag visible implies data visible)
        float* src = pbuf + (size_t)dirConsume * 100;
        float x0 = sysLoadF(&src[lane]);
        float x1 = val1 ? sysLoadF(&src[64 + lane]) : 0.f;
        if (conL) {
          nbufL[lane] = x0;
          if (val1) nbufL[64 + lane] = x1;
          ldsStoreRel(&nflagL, k);    // release covers the nbuf LDS writes
        } else {
          nbufR[lane] = x0;
          if (val1) nbufR[64 + lane] = x1;
          ldsStoreRel(&nflagR, k);
        }
        // ack AFTER loads are drained: producer may then overwrite the slot.
        VMFENCE();
        if (lane == 0) sysStoreI(&acks[dirConsume], k);
      }
    } else {
      // ---------------- A wave: post ----------------
      float y0 = (lane < 50) ? yloc : ybuf[j][lane];
      float y1 = val1 ? ybuf[j][64 + lane] : 0.f;

      float ret = wred64(fmaf(mu0, w0, mu1 * w1));
      float s2  = wred64(fmaf(y0, w0, y1 * w1));
      float sigma = sqrtf(s2 + 1e-12f);
      float z     = KAPPA_ * sigma - ret - lim;
      float act   = (z > 0.f) ? 1.f : 0.f;
      float cY    = 2.f * GAMMA_ + act * (PEN_ * KAPPA_ / sigma);
      float cM    = -(1.f + act * PEN_);

      // neighbor w (iterate k exactly — Jacobi, matches reference)
      float wl0, wl1, wn0 = 0.f, wn1 = 0.f;
      if (j == 0) {
        if (q == 0 || k == 0) { wl0 = wp0; wl1 = wp1; }
        else {
          SPIN_LDS(&nflagL, k);
          wl0 = nbufL[lane];
          wl1 = val1 ? nbufL[64 + lane] : 0.f;
        }
      } else { wl0 = wbuf[p][j - 1][lane]; wl1 = val1 ? wbuf[p][j - 1][64 + lane] : 0.f; }
      if (hasNext) {
        if (j == 2) {  // right neighbor is cross-WG (q<3 guaranteed by hasNext)
          if (k == 0) { wn0 = wp0; wn1 = wp1; }
          else {
            SPIN_LDS(&nflagR, k);
            wn0 = nbufR[lane];
            wn1 = val1 ? nbufR[64 + lane] : 0.f;
          }
        } else { wn0 = wbuf[p][j + 1][lane]; wn1 = val1 ? wbuf[p][j + 1][64 + lane] : 0.f; }
      }

      float dw0 = w0 - wl0;
      float g0  = fmaf(cM, mu0, cY * y0) + CC_ * (dw0 * rsqrtf(fmaf(dw0, dw0, 1e-10f)));
      if (hasNext) { float dn0 = wn0 - w0; g0 -= CC_ * (dn0 * rsqrtf(fmaf(dn0, dn0, 1e-10f))); }
      float v0 = fmaf(-LR_, g0, w0);
      float v1 = 0.f;
      if (val1) {
        float dw1 = w1 - wl1;
        float g1  = fmaf(cM, mu1, cY * y1) + CC_ * (dw1 * rsqrtf(fmaf(dw1, dw1, 1e-10f)));
        if (hasNext) { float dn1 = wn1 - w1; g1 -= CC_ * (dn1 * rsqrtf(fmaf(dn1, dn1, 1e-10f))); }
        v1 = fmaf(-LR_, g1, w1);
      }

      // ---- Michelot projection, warm-started (r8/r10/r11/r13-verified numerics) ----
      float a1m = val1 ? 1.f : 0.f;
      float na0 = (v0 > thp) ? 1.f : 0.f;
      float na1 = (val1 && (v1 > thp)) ? 1.f : 0.f;
      float Ssum = wred64(na0 * v0 + na1 * v1);
      float Cnt  = wred64(na0 + na1);
      if (Cnt < 0.5f) { Ssum = wred64(v0 + a1m * v1); Cnt = 100.f; }
      float theta = (Ssum - 1.f) / Cnt;
      for (int it = 0; it < 112; ++it) {
        na0 = (v0 > theta) ? 1.f : 0.f;
        na1 = (val1 && (v1 > theta)) ? 1.f : 0.f;
        float ns = wred64(na0 * v0 + na1 * v1);
        float nc = wred64(na0 + na1);
        if (nc == Cnt && ns == Ssum) break;
        if (it == 7) {  // warm-start may cycle: reset to full support (monotone)
          ns = wred64(v0 + a1m * v1);
          nc = 100.f;
        }
        Ssum = ns; Cnt = nc;
        theta = (Ssum - 1.f) / Cnt;
      }
      thp = theta;
      w0 = fmaxf(v0 - theta, 0.f);
      w1 = val1 ? fmaxf(v1 - theta, 0.f) : 0.f;

      wbuf[1 - p][j][lane] = w0;
      if (val1) wbuf[1 - p][j][64 + lane] = w1;

      // ---- cross-WG publish (boundary A): wait consumer's ack for w^k, then
      // overwrite slot with w^{k+1}, fence, flag. Skip on last iter (no consumer).
      if (isBnd && k < NIT - 1) {
        SPIN_SYS(&acks[dirPublish], k);   // consumer has read w^k (init acks=0 covers k=0)
        float* dst = pbuf + (size_t)dirPublish * 100;
        sysStoreF(&dst[lane], w0);
        if (val1) sysStoreF(&dst[64 + lane], w1);
        VMFENCE();   // only this wave's 1-2 stores outstanding -> cheap
        if (lane == 0) sysStoreI(&flags[dirPublish], k + 1);
      }
    }
    __syncthreads();
  }

  if (sec == 0) {
    float* o = out + (size_t)bh * 100;
    o[lane] = w0;
    if (val1) o[64 + lane] = w1;
  }
}

extern "C" void kernel_launch(void* const* d_in, const int* in_sizes, int n_in,
                              void* d_out, int out_size, void* d_ws, size_t ws_size,
                              hipStream_t stream) {
  const float* mu = (const float*)d_in[0];
  const float* L  = (const float*)d_in[1];
  const float* wp = (const float*)d_in[2];
  const float* cl = (const float*)d_in[3];
  float* pbuf  = (float*)d_ws;
  int*   flags = (int*)((char*)d_ws + PBUF_BYTES);
  hipMemsetAsync(flags, 0, FLAG_COUNT * sizeof(int), stream);
  hipLaunchKernelGGL(mpo_solver, dim3(512), dim3(384), 0, stream,
                     mu, L, wp, cl, (float*)d_out, pbuf, flags);
}

// Round 4
// 3427.094 us; speedup vs baseline: 1.0079x; 1.0079x over previous
//
#include <hip/hip_runtime.h>
#include <cstdint>
#include <cstddef>

// Problem constants (match reference)
#define NIT    500
#define GAMMA_ 5.0f
#define CC_    1e-3f
#define KAPPA_ 2.0627128075074256f
#define PEN_   100.0f
#define LR_    0.01f

// r18 d_ws layout: pbuf [128 b][3 boundary][2 dir][100] f32 = 307200 B (single slot
// per direction + ack handshake), then flags[768] + acks[768] ints = 6144 B.
// TOTAL ~313 KB <= 410 KB proven-safe budget (r6/r14: 617 KB layouts failed).
#define PBUF_BYTES (128*6*100*4)
#define FLAG_COUNT 1536   // [0..767] flags, [768..1535] acks

// Cross-WG primitives (r11/r13-proven): relaxed SYSTEM-scope atomic load/store ->
// coherence point, no cache-wide maintenance (r11: agent acq/rel wb/inv was a
// ~6us/iter floor), no RMW serialization (r12: RMW polls = HBM atomic storm).
#define VMFENCE() asm volatile("s_waitcnt vmcnt(0)" ::: "memory")
__device__ __forceinline__ float sysLoadF(float* p) {
  return __hip_atomic_load(p, __ATOMIC_RELAXED, __HIP_MEMORY_SCOPE_SYSTEM);
}
__device__ __forceinline__ void sysStoreF(float* p, float v) {
  __hip_atomic_store(p, v, __ATOMIC_RELAXED, __HIP_MEMORY_SCOPE_SYSTEM);
}
__device__ __forceinline__ int sysLoadI(int* p) {
  return __hip_atomic_load(p, __ATOMIC_RELAXED, __HIP_MEMORY_SCOPE_SYSTEM);
}
__device__ __forceinline__ void sysStoreI(int* p, int v) {
  __hip_atomic_store(p, v, __ATOMIC_RELAXED, __HIP_MEMORY_SCOPE_SYSTEM);
}
__device__ __forceinline__ int flagRead(int* p, int lane) {
  int f = 0;
  if (lane == 0) f = sysLoadI(p);
  return __builtin_amdgcn_readfirstlane(f);
}
// Intra-WG flag in LDS: workgroup-scope acq/rel = lgkm waits only, no cache ops.
__device__ __forceinline__ int ldsLoadAcq(int* p) {
  return __hip_atomic_load(p, __ATOMIC_ACQUIRE, __HIP_MEMORY_SCOPE_WORKGROUP);
}
__device__ __forceinline__ void ldsStoreRel(int* p, int v) {
  __hip_atomic_store(p, v, __ATOMIC_RELEASE, __HIP_MEMORY_SCOPE_WORKGROUP);
}

__device__ __forceinline__ float rdlane(float v, int lane) {
  return __int_as_float(__builtin_amdgcn_readlane(__float_as_int(v), lane));
}

// Wave64 sum via DPP, total broadcast from lane 63. Verified r5..r13.
__device__ __forceinline__ float wred64(float x) {
  int t;
  t = __builtin_amdgcn_update_dpp(0, __float_as_int(x), 0x111, 0xf, 0xf, true); x += __int_as_float(t);
  t = __builtin_amdgcn_update_dpp(0, __float_as_int(x), 0x112, 0xf, 0xf, true); x += __int_as_float(t);
  t = __builtin_amdgcn_update_dpp(0, __float_as_int(x), 0x114, 0xf, 0xf, true); x += __int_as_float(t);
  t = __builtin_amdgcn_update_dpp(0, __float_as_int(x), 0x118, 0xf, 0xf, true); x += __int_as_float(t);
  t = __builtin_amdgcn_update_dpp(0, __float_as_int(x), 0x142, 0xa, 0xf, true); x += __int_as_float(t);
  t = __builtin_amdgcn_update_dpp(0, __float_as_int(x), 0x143, 0xc, 0xf, true); x += __int_as_float(t);
  return rdlane(x, 63);
}

#define SPIN_LDS(PTR, TGT)                                                   \
  do {                                                                       \
    if (!dead) {                                                             \
      long guard_ = 0;                                                       \
      while (ldsLoadAcq(PTR) < (TGT)) {                                      \
        __builtin_amdgcn_s_sleep(1);                                         \
        if (++guard_ > (1L << 18)) { dead = true; break; }                   \
      }                                                                      \
    }                                                                        \
  } while (0)

#define SPIN_SYS(PTR, TGT)                                                   \
  do {                                                                       \
    if (!dead) {                                                             \
      long guard_ = 0;                                                       \
      while (flagRead((PTR), lane) < (TGT)) {                                \
        __builtin_amdgcn_s_sleep(1);                                         \
        if (++guard_ > (1L << 18)) { dead = true; break; }                   \
      }                                                                      \
    }                                                                        \
  } while (0)

// r19 = r18 + __launch_bounds__(384, 3). r18 post-mortem: Occupancy 17% (1 WG/CU),
// dur 2x -> the two grid halves SERIALIZED. Cause: (384,1) only requires 1 wave/EU,
// so the compiler's unified VGPR+AGPR footprint (S[100] in AGPRs; VGPR=72 reported
// excludes them) landed in the 129-256 bucket -> 2 waves/SIMD -> 8 slots/CU -> a
// second 6-wave WG (3/SIMD total) can't fit. r15's (768,1) implicitly forced
// 3 waves/SIMD (12-wave WG must fully reside). (384,3) restores that cap (=170
// regs/wave, exactly what r15 compiled into without spills) -> 2 WGs/CU co-reside
// -> the independent-domain experiment actually runs.
// Everything else byte-identical to r18; absmax must stay 0.0001220703.
// S constant-indexed only (r9: runtime index -> scratch spill -> 19.6 GB FETCH).
__global__ __launch_bounds__(384, 3) void mpo_solver(
    const float* __restrict__ mu, const float* __restrict__ L,
    const float* __restrict__ wprev, const float* __restrict__ climit,
    float* __restrict__ out, float* __restrict__ pbuf, int* __restrict__ flags)
{
  const int tid  = threadIdx.x;
  const int lane = tid & 63;
  const int wave = __builtin_amdgcn_readfirstlane(tid >> 6);  // 0..5
  const int j    = wave >> 1;       // local head 0..2
  const int sec  = wave & 1;        // 0 = A (rows 0-49 + post), 1 = B (rows 50-99)
  const int bid  = blockIdx.x;
  const int b    = bid >> 2;
  const int q    = bid & 3;         // quarter: heads 3q..3q+2
  const int h    = q * 3 + j;       // global head
  const int bh   = b * 12 + h;
  int* acks = flags + 768;

  __shared__ float wbuf[2][3][100];   // double-buffered w per head
  __shared__ float ybuf[3][100];      // y rows 50-99 per head (B-wave's half)
  __shared__ float nbufL[100];        // cross-WG left-neighbor w (head 3q-1)
  __shared__ float nbufR[100];        // cross-WG right-neighbor w (head 3q+3)
  __shared__ int   nflagL, nflagR;    // nbuf holds iter-k data -> k

  const float* Lb = L + (size_t)bh * 10000;

  // ---------- Phase 0: SYRK. Lane owns row r of S = L L^T (fp32 regs/AGPRs). ----------
  float S[100];
#pragma unroll
  for (int c = 0; c < 100; ++c) S[c] = 0.f;
  const int r = sec * 50 + lane;      // valid row iff lane < 50
  if (lane < 50) {
#pragma unroll 1
    for (int mc = 0; mc < 25; ++mc) {
      float4 lr = *(const float4*)(Lb + r * 100 + mc * 4);
#pragma unroll
      for (int c = 0; c < 100; ++c) {
        const float* Lc = Lb + c * 100 + mc * 4;   // wave-uniform -> scalar loads
        S[c] = fmaf(lr.x, Lc[0], fmaf(lr.y, Lc[1], fmaf(lr.z, Lc[2], fmaf(lr.w, Lc[3], S[c]))));
      }
    }
  }

  const bool val1 = (lane < 36);
  float mu0 = mu[(size_t)bh * 100 + lane];
  float mu1 = val1 ? mu[(size_t)bh * 100 + 64 + lane] : 0.f;
  float wp0 = wprev[b * 100 + lane];
  float wp1 = val1 ? wprev[b * 100 + 64 + lane] : 0.f;
  float lim = climit[b];

  float w0 = wp0, w1 = wp1;           // post wave's iterate (n = lane, 64+lane)

  if (sec == 0) {
    wbuf[0][j][lane] = wp0;
    if (val1) wbuf[0][j][64 + lane] = wp1;
  }
  if (tid == 0) { nflagL = 0; nflagR = 0; }
  __syncthreads();

  const bool hasNext = (h < 11);
  // Boundary m separates heads 3m+2 / 3m+3. dir id = b*6 + m*2 + {0:R->, 1:<-L}.
  const bool conL = (j == 0) && (q > 0);   // consumes head 3q-1 via dirR(q-1); also publishes dirL(q-1)
  const bool conR = (j == 2) && (q < 3);   // consumes head 3q+3 via dirL(q);   also publishes dirR(q)
  const bool isBnd = conL || conR;
  const int  dirConsume = conL ? (b * 6 + (q - 1) * 2 + 0) : (b * 6 + q * 2 + 1);
  const int  dirPublish = conL ? (b * 6 + (q - 1) * 2 + 1) : (b * 6 + q * 2 + 0);
  bool dead = false;
  float thp = -3.0e38f;               // warm Michelot seed; k=0 -> full support

  for (int k = 0; k < NIT; ++k) {
    const int p = k & 1;

    // ---------- matvec y = S * w_k: wave-uniform ds_read_b128 broadcast ----------
    float yloc;
    {
      float a0 = 0.f, a1 = 0.f, a2 = 0.f, a3 = 0.f;
      const float* wrow = wbuf[p][j];
#pragma unroll
      for (int qq = 0; qq < 25; ++qq) {
        float4 wq = *(const float4*)(wrow + qq * 4);
        a0 = fmaf(wq.x, S[qq * 4 + 0], a0);
        a1 = fmaf(wq.y, S[qq * 4 + 1], a1);
        a2 = fmaf(wq.z, S[qq * 4 + 2], a2);
        a3 = fmaf(wq.w, S[qq * 4 + 3], a3);
      }
      yloc = (a0 + a2) + (a1 + a3);
      if (sec == 1 && lane < 50) ybuf[j][50 + lane] = yloc;  // only B publishes its half
    }
    __syncthreads();

    // ================= post window =================
    if (sec == 1) {
      // ---- B wave of a boundary head: delegated cross-WG read (otherwise idle) ----
      if (isBnd && k > 0) {
        SPIN_SYS(&flags[dirConsume], k);
        // two-phase: data issued only after flag>=k observed (producer fenced
        // data before flag -> flag visible implies data visible)
        float* src = pbuf + (size_t)dirConsume * 100;
        float x0 = sysLoadF(&src[lane]);
        float x1 = val1 ? sysLoadF(&src[64 + lane]) : 0.f;
        if (conL) {
          nbufL[lane] = x0;
          if (val1) nbufL[64 + lane] = x1;
          ldsStoreRel(&nflagL, k);    // release covers the nbuf LDS writes
        } else {
          nbufR[lane] = x0;
          if (val1) nbufR[64 + lane] = x1;
          ldsStoreRel(&nflagR, k);
        }
        // ack AFTER loads are drained: producer may then overwrite the slot.
        VMFENCE();
        if (lane == 0) sysStoreI(&acks[dirConsume], k);
      }
    } else {
      // ---------------- A wave: post ----------------
      float y0 = (lane < 50) ? yloc : ybuf[j][lane];
      float y1 = val1 ? ybuf[j][64 + lane] : 0.f;

      float ret = wred64(fmaf(mu0, w0, mu1 * w1));
      float s2  = wred64(fmaf(y0, w0, y1 * w1));
      float sigma = sqrtf(s2 + 1e-12f);
      float z     = KAPPA_ * sigma - ret - lim;
      float act   = (z > 0.f) ? 1.f : 0.f;
      float cY    = 2.f * GAMMA_ + act * (PEN_ * KAPPA_ / sigma);
      float cM    = -(1.f + act * PEN_);

      // neighbor w (iterate k exactly — Jacobi, matches reference)
      float wl0, wl1, wn0 = 0.f, wn1 = 0.f;
      if (j == 0) {
        if (q == 0 || k == 0) { wl0 = wp0; wl1 = wp1; }
        else {
          SPIN_LDS(&nflagL, k);
          wl0 = nbufL[lane];
          wl1 = val1 ? nbufL[64 + lane] : 0.f;
        }
      } else { wl0 = wbuf[p][j - 1][lane]; wl1 = val1 ? wbuf[p][j - 1][64 + lane] : 0.f; }
      if (hasNext) {
        if (j == 2) {  // right neighbor is cross-WG (q<3 guaranteed by hasNext)
          if (k == 0) { wn0 = wp0; wn1 = wp1; }
          else {
            SPIN_LDS(&nflagR, k);
            wn0 = nbufR[lane];
            wn1 = val1 ? nbufR[64 + lane] : 0.f;
          }
        } else { wn0 = wbuf[p][j + 1][lane]; wn1 = val1 ? wbuf[p][j + 1][64 + lane] : 0.f; }
      }

      float dw0 = w0 - wl0;
      float g0  = fmaf(cM, mu0, cY * y0) + CC_ * (dw0 * rsqrtf(fmaf(dw0, dw0, 1e-10f)));
      if (hasNext) { float dn0 = wn0 - w0; g0 -= CC_ * (dn0 * rsqrtf(fmaf(dn0, dn0, 1e-10f))); }
      float v0 = fmaf(-LR_, g0, w0);
      float v1 = 0.f;
      if (val1) {
        float dw1 = w1 - wl1;
        float g1  = fmaf(cM, mu1, cY * y1) + CC_ * (dw1 * rsqrtf(fmaf(dw1, dw1, 1e-10f)));
        if (hasNext) { float dn1 = wn1 - w1; g1 -= CC_ * (dn1 * rsqrtf(fmaf(dn1, dn1, 1e-10f))); }
        v1 = fmaf(-LR_, g1, w1);
      }

      // ---- Michelot projection, warm-started (r8/r10/r11/r13-verified numerics) ----
      float a1m = val1 ? 1.f : 0.f;
      float na0 = (v0 > thp) ? 1.f : 0.f;
      float na1 = (val1 && (v1 > thp)) ? 1.f : 0.f;
      float Ssum = wred64(na0 * v0 + na1 * v1);
      float Cnt  = wred64(na0 + na1);
      if (Cnt < 0.5f) { Ssum = wred64(v0 + a1m * v1); Cnt = 100.f; }
      float theta = (Ssum - 1.f) / Cnt;
      for (int it = 0; it < 112; ++it) {
        na0 = (v0 > theta) ? 1.f : 0.f;
        na1 = (val1 && (v1 > theta)) ? 1.f : 0.f;
        float ns = wred64(na0 * v0 + na1 * v1);
        float nc = wred64(na0 + na1);
        if (nc == Cnt && ns == Ssum) break;
        if (it == 7) {  // warm-start may cycle: reset to full support (monotone)
          ns = wred64(v0 + a1m * v1);
          nc = 100.f;
        }
        Ssum = ns; Cnt = nc;
        theta = (Ssum - 1.f) / Cnt;
      }
      thp = theta;
      w0 = fmaxf(v0 - theta, 0.f);
      w1 = val1 ? fmaxf(v1 - theta, 0.f) : 0.f;

      wbuf[1 - p][j][lane] = w0;
      if (val1) wbuf[1 - p][j][64 + lane] = w1;

      // ---- cross-WG publish (boundary A): wait consumer's ack for w^k, then
      // overwrite slot with w^{k+1}, fence, flag. Skip on last iter (no consumer).
      if (isBnd && k < NIT - 1) {
        SPIN_SYS(&acks[dirPublish], k);   // consumer has read w^k (init acks=0 covers k=0)
        float* dst = pbuf + (size_t)dirPublish * 100;
        sysStoreF(&dst[lane], w0);
        if (val1) sysStoreF(&dst[64 + lane], w1);
        VMFENCE();   // only this wave's 1-2 stores outstanding -> cheap
        if (lane == 0) sysStoreI(&flags[dirPublish], k + 1);
      }
    }
    __syncthreads();
  }

  if (sec == 0) {
    float* o = out + (size_t)bh * 100;
    o[lane] = w0;
    if (val1) o[64 + lane] = w1;
  }
}

extern "C" void kernel_launch(void* const* d_in, const int* in_sizes, int n_in,
                              void* d_out, int out_size, void* d_ws, size_t ws_size,
                              hipStream_t stream) {
  const float* mu = (const float*)d_in[0];
  const float* L  = (const float*)d_in[1];
  const float* wp = (const float*)d_in[2];
  const float* cl = (const float*)d_in[3];
  float* pbuf  = (float*)d_ws;
  int*   flags = (int*)((char*)d_ws + PBUF_BYTES);
  hipMemsetAsync(flags, 0, FLAG_COUNT * sizeof(int), stream);
  hipLaunchKernelGGL(mpo_solver, dim3(512), dim3(384), 0, stream,
                     mu, L, wp, cl, (float*)d_out, pbuf, flags);
}

// Round 5
// 1856.407 us; speedup vs baseline: 1.8606x; 1.8461x over previous
//
#include <hip/hip_runtime.h>
#include <cstdint>
#include <cstddef>

// Problem constants (match reference)
#define NIT    500
#define GAMMA_ 5.0f
#define CC_    1e-3f
#define KAPPA_ 2.0627128075074256f
#define PEN_   100.0f
#define LR_    0.01f

// d_ws layout: pbuf [128 b][2 dir][2 parity][100] f32 = 204800 B, then flags [256] int.
// TOTAL ~206 KB. r6/r14 post-mortem: both 617 KB layouts failed with garbage-neighbor
// signatures while every <=410 KB layout passed -> treat ws budget as ~512 KB hard.
#define PBUF_BYTES (128*2*2*100*4)
#define FLAG_COUNT 256

// Cross-WG primitives (r11/r13-proven): relaxed SYSTEM-scope atomic load/store ->
// coherence point, no cache-wide maintenance (r11: agent acq/rel wb/inv was a
// ~6us/iter floor), no RMW serialization (r12: RMW polls = HBM atomic storm).
#define VMFENCE() asm volatile("s_waitcnt vmcnt(0)" ::: "memory")
__device__ __forceinline__ float sysLoadF(float* p) {
  return __hip_atomic_load(p, __ATOMIC_RELAXED, __HIP_MEMORY_SCOPE_SYSTEM);
}
__device__ __forceinline__ void sysStoreF(float* p, float v) {
  __hip_atomic_store(p, v, __ATOMIC_RELAXED, __HIP_MEMORY_SCOPE_SYSTEM);
}
__device__ __forceinline__ int sysLoadI(int* p) {
  return __hip_atomic_load(p, __ATOMIC_RELAXED, __HIP_MEMORY_SCOPE_SYSTEM);
}
__device__ __forceinline__ void sysStoreI(int* p, int v) {
  __hip_atomic_store(p, v, __ATOMIC_RELAXED, __HIP_MEMORY_SCOPE_SYSTEM);
}
__device__ __forceinline__ int flagRead(int* p, int lane) {
  int f = 0;
  if (lane == 0) f = sysLoadI(p);
  return __builtin_amdgcn_readfirstlane(f);
}
// Intra-WG flag in LDS: workgroup-scope acq/rel = lgkm waits only, no cache ops.
__device__ __forceinline__ int ldsLoadAcq(int* p) {
  return __hip_atomic_load(p, __ATOMIC_ACQUIRE, __HIP_MEMORY_SCOPE_WORKGROUP);
}
__device__ __forceinline__ void ldsStoreRel(int* p, int v) {
  __hip_atomic_store(p, v, __ATOMIC_RELEASE, __HIP_MEMORY_SCOPE_WORKGROUP);
}

__device__ __forceinline__ float rdlane(float v, int lane) {
  return __int_as_float(__builtin_amdgcn_readlane(__float_as_int(v), lane));
}

// Wave64 sum via DPP, total broadcast from lane 63. Verified r5..r13.
__device__ __forceinline__ float wred64(float x) {
  int t;
  t = __builtin_amdgcn_update_dpp(0, __float_as_int(x), 0x111, 0xf, 0xf, true); x += __int_as_float(t);
  t = __builtin_amdgcn_update_dpp(0, __float_as_int(x), 0x112, 0xf, 0xf, true); x += __int_as_float(t);
  t = __builtin_amdgcn_update_dpp(0, __float_as_int(x), 0x114, 0xf, 0xf, true); x += __int_as_float(t);
  t = __builtin_amdgcn_update_dpp(0, __float_as_int(x), 0x118, 0xf, 0xf, true); x += __int_as_float(t);
  t = __builtin_amdgcn_update_dpp(0, __float_as_int(x), 0x142, 0xa, 0xf, true); x += __int_as_float(t);
  t = __builtin_amdgcn_update_dpp(0, __float_as_int(x), 0x143, 0xc, 0xf, true); x += __int_as_float(t);
  return rdlane(x, 63);
}

// r20 = r15 skeleton (best measured 1651us: 768 thr, 2 barriers/iter, delegated
// boundary read) + MICHELOT WARM-START REMOVED + ret-wred hoisted above matvec.
//
// Post-mortems: r16 flag-desync +4%; r17 SIMD remap ~flat; r18/r19 384-thr WGs
// serialized grid halves (occ 17%, dur 2x) regardless of launch_bounds. REVERTED.
//
// r20 rationale (counter-derived): VALUBusy 40% @ 7920 cy/iter => ~1060 VALU
// instrs/head/iter; static count outside Michelot is ~420 => ~600 instrs in the
// projection loop = ~17 passes/iter. The warm-start path must be cycling and
// taking the it==7 full-support reset nearly every iteration (7 wasted passes),
// making Michelot's serial DPP latency (~2900 cy) the period-setter. Fix: always
// start from full support (monotone, ~5-7 passes, no cycle/reset branch). The
// projection fixed point is unique and final theta is the identical reduction
// over the identical final support -> absmax must stay exactly 0.0001220703.
// S constant-indexed only (r9: runtime index -> scratch spill -> 19.6 GB FETCH).
__global__ __launch_bounds__(768, 1) void mpo_solver(
    const float* __restrict__ mu, const float* __restrict__ L,
    const float* __restrict__ wprev, const float* __restrict__ climit,
    float* __restrict__ out, float* __restrict__ pbuf, int* __restrict__ flags)
{
  const int tid  = threadIdx.x;
  const int lane = tid & 63;
  const int wave = __builtin_amdgcn_readfirstlane(tid >> 6);  // 0..11
  const int j    = wave >> 1;       // local head 0..5
  const int sec  = wave & 1;        // 0 = rows 0-49 + post, 1 = rows 50-99
  const int bid  = blockIdx.x;
  const int b    = bid & 127;
  const int half = bid >> 7;        // 0: heads 0-5, 1: heads 6-11
  const int h    = half * 6 + j;    // global head
  const int bh   = b * 12 + h;

  __shared__ float wbuf[2][6][100];   // double-buffered w per head
  __shared__ float ybuf[6][100];      // y rows 50-99 per head (B-wave's half)
  __shared__ float nbuf[100];         // delegated cross-WG neighbor w (one boundary head/WG)
  __shared__ int   nflag;             // nbuf holds iter-k data -> k

  const float* Lb = L + (size_t)bh * 10000;

  // ---------- Phase 0: SYRK. Lane owns row r of S = L L^T (fp32 regs/AGPRs). ----------
  float S[100];
#pragma unroll
  for (int c = 0; c < 100; ++c) S[c] = 0.f;
  const int r = sec * 50 + lane;      // valid row iff lane < 50
  if (lane < 50) {
#pragma unroll 1
    for (int mc = 0; mc < 25; ++mc) {
      float4 lr = *(const float4*)(Lb + r * 100 + mc * 4);
#pragma unroll
      for (int c = 0; c < 100; ++c) {
        const float* Lc = Lb + c * 100 + mc * 4;   // wave-uniform -> scalar loads
        S[c] = fmaf(lr.x, Lc[0], fmaf(lr.y, Lc[1], fmaf(lr.z, Lc[2], fmaf(lr.w, Lc[3], S[c]))));
      }
    }
  }

  const bool val1 = (lane < 36);
  float mu0 = mu[(size_t)bh * 100 + lane];
  float mu1 = val1 ? mu[(size_t)bh * 100 + 64 + lane] : 0.f;
  float wp0 = wprev[b * 100 + lane];
  float wp1 = val1 ? wprev[b * 100 + 64 + lane] : 0.f;
  float lim = climit[b];

  float w0 = wp0, w1 = wp1;           // post wave's iterate (n = lane, 64+lane)

  if (sec == 0) {
    wbuf[0][j][lane] = wp0;
    if (val1) wbuf[0][j][64 + lane] = wp1;
  }
  if (tid == 0) nflag = 0;
  __syncthreads();

  const bool hasNext = (h < 11);
  const bool isPubL  = (half == 0) && (j == 5);  // boundary head: publishes 5, consumes 6
  const bool isPubH  = (half == 1) && (j == 0);  // boundary head: publishes 6, consumes 5
  const bool isBnd   = isPubL || isPubH;
  const int  flagPub = isPubL ? (b * 2 + 0) : (b * 2 + 1);
  const int  flagCon = isPubL ? (b * 2 + 1) : (b * 2 + 0);
  bool dead = false;

  for (int k = 0; k < NIT; ++k) {
    const int p = k & 1;

    // ret depends only on w^k (regs) and mu -> hoist its DPP chain above the
    // matvec so the latency hides under the FMA stream (value bitwise identical).
    float ret = 0.f;
    if (sec == 0) ret = wred64(fmaf(mu0, w0, mu1 * w1));

    // ---------- matvec y = S * w_k: wave-uniform ds_read_b128 broadcast ----------
    float yloc;
    {
      float a0 = 0.f, a1 = 0.f, a2 = 0.f, a3 = 0.f;
      const float* wrow = wbuf[p][j];
#pragma unroll
      for (int q = 0; q < 25; ++q) {
        float4 wq = *(const float4*)(wrow + q * 4);
        a0 = fmaf(wq.x, S[q * 4 + 0], a0);
        a1 = fmaf(wq.y, S[q * 4 + 1], a1);
        a2 = fmaf(wq.z, S[q * 4 + 2], a2);
        a3 = fmaf(wq.w, S[q * 4 + 3], a3);
      }
      yloc = (a0 + a2) + (a1 + a3);
      if (sec == 1 && lane < 50) ybuf[j][50 + lane] = yloc;  // only B publishes its half
    }
    __syncthreads();

    // ================= post window =================
    if (sec == 1) {
      // ---- B wave of the boundary head: delegated cross-WG read (otherwise idle) ----
      if (isBnd && k > 0) {
        if (!dead) {
          long guard = 0;
          while (flagRead(&flags[flagCon], lane) < k) {
            __builtin_amdgcn_s_sleep(1);
            if (++guard > (1L << 18)) { dead = true; break; }
          }
        }
        // two-phase: data issued only after flag>=k observed (producer fenced
        // data before flag -> flag visible implies data visible)
        float* src = pbuf + ((size_t)flagCon * 2 + (k & 1)) * 100;
        nbuf[lane] = sysLoadF(&src[lane]);
        if (val1) nbuf[64 + lane] = sysLoadF(&src[64 + lane]);
        ldsStoreRel(&nflag, k);   // release covers the nbuf LDS writes
      }
    } else {
      // ---------------- A wave: post ----------------
      float y0 = (lane < 50) ? yloc : ybuf[j][lane];
      float y1 = val1 ? ybuf[j][64 + lane] : 0.f;

      float s2  = wred64(fmaf(y0, w0, y1 * w1));
      float sigma = sqrtf(s2 + 1e-12f);
      float z     = KAPPA_ * sigma - ret - lim;
      float act   = (z > 0.f) ? 1.f : 0.f;
      float cY    = 2.f * GAMMA_ + act * (PEN_ * KAPPA_ / sigma);
      float cM    = -(1.f + act * PEN_);

      // neighbor w (iterate k exactly — Jacobi, matches reference)
      float wl0, wl1, wn0 = 0.f, wn1 = 0.f;
      if (j == 0) {
        if (half == 0 || k == 0) { wl0 = wp0; wl1 = wp1; }
        else {
          if (!dead) {
            long guard = 0;
            while (ldsLoadAcq(&nflag) < k) {
              __builtin_amdgcn_s_sleep(1);
              if (++guard > (1L << 18)) { dead = true; break; }
            }
          }
          wl0 = nbuf[lane];
          wl1 = val1 ? nbuf[64 + lane] : 0.f;
        }
      } else { wl0 = wbuf[p][j - 1][lane]; wl1 = val1 ? wbuf[p][j - 1][64 + lane] : 0.f; }
      if (hasNext) {
        if (j == 5) {  // half==0 boundary: next is head 6 (delegated)
          if (k == 0) { wn0 = wp0; wn1 = wp1; }
          else {
            if (!dead) {
              long guard = 0;
              while (ldsLoadAcq(&nflag) < k) {
                __builtin_amdgcn_s_sleep(1);
                if (++guard > (1L << 18)) { dead = true; break; }
              }
            }
            wn0 = nbuf[lane];
            wn1 = val1 ? nbuf[64 + lane] : 0.f;
          }
        } else { wn0 = wbuf[p][j + 1][lane]; wn1 = val1 ? wbuf[p][j + 1][64 + lane] : 0.f; }
      }

      float dw0 = w0 - wl0;
      float g0  = fmaf(cM, mu0, cY * y0) + CC_ * (dw0 * rsqrtf(fmaf(dw0, dw0, 1e-10f)));
      if (hasNext) { float dn0 = wn0 - w0; g0 -= CC_ * (dn0 * rsqrtf(fmaf(dn0, dn0, 1e-10f))); }
      float v0 = fmaf(-LR_, g0, w0);
      float v1 = 0.f;
      if (val1) {
        float dw1 = w1 - wl1;
        float g1  = fmaf(cM, mu1, cY * y1) + CC_ * (dw1 * rsqrtf(fmaf(dw1, dw1, 1e-10f)));
        if (hasNext) { float dn1 = wn1 - w1; g1 -= CC_ * (dn1 * rsqrtf(fmaf(dn1, dn1, 1e-10f))); }
        v1 = fmaf(-LR_, g1, w1);
      }

      // ---- Michelot projection, FULL-SUPPORT START (r20). Warm start removed:
      // counters showed ~17 passes/iter = warm-path cycling through the it==7
      // reset nearly every iteration. Full-support start is monotone (support
      // only shrinks), converges in ~5-7 passes, no reset branch. Fixed point
      // (final support + theta) is identical -> same w, same absmax.
      float a1m = val1 ? 1.f : 0.f;
      float Ssum = wred64(v0 + a1m * v1);
      float Cnt  = 100.f;
      float theta = (Ssum - 1.f) / Cnt;
      for (int it = 0; it < 112; ++it) {
        float na0 = (v0 > theta) ? 1.f : 0.f;
        float na1 = (val1 && (v1 > theta)) ? 1.f : 0.f;
        float ns = wred64(na0 * v0 + na1 * v1);
        float nc = wred64(na0 + na1);
        if (nc == Cnt && ns == Ssum) break;
        Ssum = ns; Cnt = nc;
        theta = (Ssum - 1.f) / Cnt;
      }
      w0 = fmaxf(v0 - theta, 0.f);
      w1 = val1 ? fmaxf(v1 - theta, 0.f) : 0.f;

      wbuf[1 - p][j][lane] = w0;
      if (val1) wbuf[1 - p][j][64 + lane] = w1;

      // ---- IMMEDIATE cross-WG publish: data, fence, flag (boundary A only) ----
      if (isBnd) {
        float* dst = pbuf + ((size_t)flagPub * 2 + ((k + 1) & 1)) * 100;
        sysStoreF(&dst[lane], w0);
        if (val1) sysStoreF(&dst[64 + lane], w1);
        VMFENCE();   // only this wave's 1-2 stores outstanding -> cheap
        if (lane == 0) sysStoreI(&flags[flagPub], k + 1);
      }
    }
    __syncthreads();
  }

  if (sec == 0) {
    float* o = out + (size_t)bh * 100;
    o[lane] = w0;
    if (val1) o[64 + lane] = w1;
  }
}

extern "C" void kernel_launch(void* const* d_in, const int* in_sizes, int n_in,
                              void* d_out, int out_size, void* d_ws, size_t ws_size,
                              hipStream_t stream) {
  const float* mu = (const float*)d_in[0];
  const float* L  = (const float*)d_in[1];
  const float* wp = (const float*)d_in[2];
  const float* cl = (const float*)d_in[3];
  float* pbuf  = (float*)d_ws;
  int*   flags = (int*)((char*)d_ws + PBUF_BYTES);
  hipMemsetAsync(flags, 0, FLAG_COUNT * sizeof(int), stream);
  hipLaunchKernelGGL(mpo_solver, dim3(256), dim3(768), 0, stream,
                     mu, L, wp, cl, (float*)d_out, pbuf, flags);
}

// Round 6
// 1641.619 us; speedup vs baseline: 2.1040x; 1.1308x over previous
//
#include <hip/hip_runtime.h>
#include <cstdint>
#include <cstddef>

// Problem constants (match reference)
#define NIT    500
#define GAMMA_ 5.0f
#define CC_    1e-3f
#define KAPPA_ 2.0627128075074256f
#define PEN_   100.0f
#define LR_    0.01f

// d_ws layout: pbuf [128 b][2 dir][2 parity][100] f32 = 204800 B, then flags [256] int.
// TOTAL ~206 KB. r6/r14 post-mortem: both 617 KB layouts failed with garbage-neighbor
// signatures while every <=410 KB layout passed -> treat ws budget as ~512 KB hard.
#define PBUF_BYTES (128*2*2*100*4)
#define FLAG_COUNT 256

// Cross-WG primitives (r11/r13-proven): relaxed SYSTEM-scope atomic load/store ->
// coherence point, no cache-wide maintenance (r11: agent acq/rel wb/inv was a
// ~6us/iter floor), no RMW serialization (r12: RMW polls = HBM atomic storm).
#define VMFENCE() asm volatile("s_waitcnt vmcnt(0)" ::: "memory")
// r21: raw barrier with LDS-only drain. __syncthreads() also drains vmcnt(0),
// which convoys all 12 waves behind the boundary wave's LLC store-acks. The only
// inter-wave data inside the WG is LDS (lgkm); cross-WG ordering is carried by
// the explicit VMFENCE protocol. "memory" clobber pins LDS ops across it.
#define BARRIER() do { asm volatile("s_waitcnt lgkmcnt(0)" ::: "memory"); \
                       __builtin_amdgcn_s_barrier(); } while (0)
__device__ __forceinline__ float sysLoadF(float* p) {
  return __hip_atomic_load(p, __ATOMIC_RELAXED, __HIP_MEMORY_SCOPE_SYSTEM);
}
__device__ __forceinline__ void sysStoreF(float* p, float v) {
  __hip_atomic_store(p, v, __ATOMIC_RELAXED, __HIP_MEMORY_SCOPE_SYSTEM);
}
__device__ __forceinline__ int sysLoadI(int* p) {
  return __hip_atomic_load(p, __ATOMIC_RELAXED, __HIP_MEMORY_SCOPE_SYSTEM);
}
__device__ __forceinline__ void sysStoreI(int* p, int v) {
  __hip_atomic_store(p, v, __ATOMIC_RELAXED, __HIP_MEMORY_SCOPE_SYSTEM);
}
__device__ __forceinline__ int flagRead(int* p, int lane) {
  int f = 0;
  if (lane == 0) f = sysLoadI(p);
  return __builtin_amdgcn_readfirstlane(f);
}
// Intra-WG flag in LDS: workgroup-scope acq/rel = lgkm waits only, no cache ops.
__device__ __forceinline__ int ldsLoadAcq(int* p) {
  return __hip_atomic_load(p, __ATOMIC_ACQUIRE, __HIP_MEMORY_SCOPE_WORKGROUP);
}
__device__ __forceinline__ void ldsStoreRel(int* p, int v) {
  __hip_atomic_store(p, v, __ATOMIC_RELEASE, __HIP_MEMORY_SCOPE_WORKGROUP);
}

__device__ __forceinline__ float rdlane(float v, int lane) {
  return __int_as_float(__builtin_amdgcn_readlane(__float_as_int(v), lane));
}

// Wave64 sum via DPP, total broadcast from lane 63. Verified r5..r13.
__device__ __forceinline__ float wred64(float x) {
  int t;
  t = __builtin_amdgcn_update_dpp(0, __float_as_int(x), 0x111, 0xf, 0xf, true); x += __int_as_float(t);
  t = __builtin_amdgcn_update_dpp(0, __float_as_int(x), 0x112, 0xf, 0xf, true); x += __int_as_float(t);
  t = __builtin_amdgcn_update_dpp(0, __float_as_int(x), 0x114, 0xf, 0xf, true); x += __int_as_float(t);
  t = __builtin_amdgcn_update_dpp(0, __float_as_int(x), 0x118, 0xf, 0xf, true); x += __int_as_float(t);
  t = __builtin_amdgcn_update_dpp(0, __float_as_int(x), 0x142, 0xa, 0xf, true); x += __int_as_float(t);
  t = __builtin_amdgcn_update_dpp(0, __float_as_int(x), 0x143, 0xc, 0xf, true); x += __int_as_float(t);
  return rdlane(x, 63);
}

// r21 = r15 skeleton (best: 1651us) with WARM-START MICHELOT RESTORED (r20 showed
// full-support start = +13% instrs, +12% time -> warm start works AND the kernel
// is instruction-throughput-proportional) + three zero-numerics-risk edits:
//  1. ret-wred hoisted above matvec (DPP chain hides under FMA stream).
//  2. Raw lgkm-only barriers (BARRIER()): __syncthreads' vmcnt(0) drain convoyed
//     all 12 waves behind the boundary wave's LLC store-acks.
//  3. Split publish: data stores at end of post(k) (no fence); VMFENCE + flag at
//     START of iter k+1 -> acks retire during barrier-2, fence is near-free, flag
//     store flies under the matvec. Data->fence->flag order preserved; ring-2
//     overwrite safety only gains slack; consumer gains ~1 phase skew tolerance.
// Arithmetic bitwise-identical to r15 -> absmax must stay exactly 0.0001220703.
// Post-mortems: r16 flag-desync +4% (LDS acq gates ~120cy each); r17 SIMD remap
// flat; r18/r19 384-thr WGs serialized halves (occ 17%) -> all reverted.
// S constant-indexed only (r9: runtime index -> scratch spill -> 19.6 GB FETCH).
__global__ __launch_bounds__(768, 1) void mpo_solver(
    const float* __restrict__ mu, const float* __restrict__ L,
    const float* __restrict__ wprev, const float* __restrict__ climit,
    float* __restrict__ out, float* __restrict__ pbuf, int* __restrict__ flags)
{
  const int tid  = threadIdx.x;
  const int lane = tid & 63;
  const int wave = __builtin_amdgcn_readfirstlane(tid >> 6);  // 0..11
  const int j    = wave >> 1;       // local head 0..5
  const int sec  = wave & 1;        // 0 = rows 0-49 + post, 1 = rows 50-99
  const int bid  = blockIdx.x;
  const int b    = bid & 127;
  const int half = bid >> 7;        // 0: heads 0-5, 1: heads 6-11
  const int h    = half * 6 + j;    // global head
  const int bh   = b * 12 + h;

  __shared__ float wbuf[2][6][100];   // double-buffered w per head
  __shared__ float ybuf[6][100];      // y rows 50-99 per head (B-wave's half)
  __shared__ float nbuf[100];         // delegated cross-WG neighbor w (one boundary head/WG)
  __shared__ int   nflag;             // nbuf holds iter-k data -> k

  const float* Lb = L + (size_t)bh * 10000;

  // ---------- Phase 0: SYRK. Lane owns row r of S = L L^T (fp32 regs/AGPRs). ----------
  float S[100];
#pragma unroll
  for (int c = 0; c < 100; ++c) S[c] = 0.f;
  const int r = sec * 50 + lane;      // valid row iff lane < 50
  if (lane < 50) {
#pragma unroll 1
    for (int mc = 0; mc < 25; ++mc) {
      float4 lr = *(const float4*)(Lb + r * 100 + mc * 4);
#pragma unroll
      for (int c = 0; c < 100; ++c) {
        const float* Lc = Lb + c * 100 + mc * 4;   // wave-uniform -> scalar loads
        S[c] = fmaf(lr.x, Lc[0], fmaf(lr.y, Lc[1], fmaf(lr.z, Lc[2], fmaf(lr.w, Lc[3], S[c]))));
      }
    }
  }

  const bool val1 = (lane < 36);
  float mu0 = mu[(size_t)bh * 100 + lane];
  float mu1 = val1 ? mu[(size_t)bh * 100 + 64 + lane] : 0.f;
  float wp0 = wprev[b * 100 + lane];
  float wp1 = val1 ? wprev[b * 100 + 64 + lane] : 0.f;
  float lim = climit[b];

  float w0 = wp0, w1 = wp1;           // post wave's iterate (n = lane, 64+lane)

  if (sec == 0) {
    wbuf[0][j][lane] = wp0;
    if (val1) wbuf[0][j][64 + lane] = wp1;
  }
  if (tid == 0) nflag = 0;
  __syncthreads();                    // init barrier (full semantics, once)

  const bool hasNext = (h < 11);
  const bool isPubL  = (half == 0) && (j == 5);  // boundary head: publishes 5, consumes 6
  const bool isPubH  = (half == 1) && (j == 0);  // boundary head: publishes 6, consumes 5
  const bool isBnd   = isPubL || isPubH;
  const int  flagPub = isPubL ? (b * 2 + 0) : (b * 2 + 1);
  const int  flagCon = isPubL ? (b * 2 + 1) : (b * 2 + 0);
  bool dead = false;
  float thp = -3.0e38f;               // warm Michelot seed; k=0 -> full support

  for (int k = 0; k < NIT; ++k) {
    const int p = k & 1;

    // ---- deferred cross-WG flag publish for w^k (data stores issued at end of
    // post(k-1); acks retired during barrier-2 -> fence near-free; flag store
    // flies under the matvec, never between the barriers).
    if (sec == 0 && isBnd && k > 0) {
      VMFENCE();
      if (lane == 0) sysStoreI(&flags[flagPub], k);
    }

    // ret depends only on w^k (regs) and mu -> hoist its DPP chain above the
    // matvec so the latency hides under the FMA stream (value bitwise identical).
    float ret = 0.f;
    if (sec == 0) ret = wred64(fmaf(mu0, w0, mu1 * w1));

    // ---------- matvec y = S * w_k: wave-uniform ds_read_b128 broadcast ----------
    float yloc;
    {
      float a0 = 0.f, a1 = 0.f, a2 = 0.f, a3 = 0.f;
      const float* wrow = wbuf[p][j];
#pragma unroll
      for (int q = 0; q < 25; ++q) {
        float4 wq = *(const float4*)(wrow + q * 4);
        a0 = fmaf(wq.x, S[q * 4 + 0], a0);
        a1 = fmaf(wq.y, S[q * 4 + 1], a1);
        a2 = fmaf(wq.z, S[q * 4 + 2], a2);
        a3 = fmaf(wq.w, S[q * 4 + 3], a3);
      }
      yloc = (a0 + a2) + (a1 + a3);
      if (sec == 1 && lane < 50) ybuf[j][50 + lane] = yloc;  // only B publishes its half
    }
    BARRIER();

    // ================= post window =================
    if (sec == 1) {
      // ---- B wave of the boundary head: delegated cross-WG read (otherwise idle) ----
      if (isBnd && k > 0) {
        if (!dead) {
          long guard = 0;
          while (flagRead(&flags[flagCon], lane) < k) {
            __builtin_amdgcn_s_sleep(1);
            if (++guard > (1L << 18)) { dead = true; break; }
          }
        }
        // two-phase: data issued only after flag>=k observed (producer fenced
        // data before flag -> flag visible implies data visible)
        float* src = pbuf + ((size_t)flagCon * 2 + (k & 1)) * 100;
        nbuf[lane] = sysLoadF(&src[lane]);
        if (val1) nbuf[64 + lane] = sysLoadF(&src[64 + lane]);
        ldsStoreRel(&nflag, k);   // release covers the nbuf LDS writes
      }
    } else {
      // ---------------- A wave: post ----------------
      float y0 = (lane < 50) ? yloc : ybuf[j][lane];
      float y1 = val1 ? ybuf[j][64 + lane] : 0.f;

      float s2  = wred64(fmaf(y0, w0, y1 * w1));
      float sigma = sqrtf(s2 + 1e-12f);
      float z     = KAPPA_ * sigma - ret - lim;
      float act   = (z > 0.f) ? 1.f : 0.f;
      float cY    = 2.f * GAMMA_ + act * (PEN_ * KAPPA_ / sigma);
      float cM    = -(1.f + act * PEN_);

      // neighbor w (iterate k exactly — Jacobi, matches reference)
      float wl0, wl1, wn0 = 0.f, wn1 = 0.f;
      if (j == 0) {
        if (half == 0 || k == 0) { wl0 = wp0; wl1 = wp1; }
        else {
          if (!dead) {
            long guard = 0;
            while (ldsLoadAcq(&nflag) < k) {
              __builtin_amdgcn_s_sleep(1);
              if (++guard > (1L << 18)) { dead = true; break; }
            }
          }
          wl0 = nbuf[lane];
          wl1 = val1 ? nbuf[64 + lane] : 0.f;
        }
      } else { wl0 = wbuf[p][j - 1][lane]; wl1 = val1 ? wbuf[p][j - 1][64 + lane] : 0.f; }
      if (hasNext) {
        if (j == 5) {  // half==0 boundary: next is head 6 (delegated)
          if (k == 0) { wn0 = wp0; wn1 = wp1; }
          else {
            if (!dead) {
              long guard = 0;
              while (ldsLoadAcq(&nflag) < k) {
                __builtin_amdgcn_s_sleep(1);
                if (++guard > (1L << 18)) { dead = true; break; }
              }
            }
            wn0 = nbuf[lane];
            wn1 = val1 ? nbuf[64 + lane] : 0.f;
          }
        } else { wn0 = wbuf[p][j + 1][lane]; wn1 = val1 ? wbuf[p][j + 1][64 + lane] : 0.f; }
      }

      float dw0 = w0 - wl0;
      float g0  = fmaf(cM, mu0, cY * y0) + CC_ * (dw0 * rsqrtf(fmaf(dw0, dw0, 1e-10f)));
      if (hasNext) { float dn0 = wn0 - w0; g0 -= CC_ * (dn0 * rsqrtf(fmaf(dn0, dn0, 1e-10f))); }
      float v0 = fmaf(-LR_, g0, w0);
      float v1 = 0.f;
      if (val1) {
        float dw1 = w1 - wl1;
        float g1  = fmaf(cM, mu1, cY * y1) + CC_ * (dw1 * rsqrtf(fmaf(dw1, dw1, 1e-10f)));
        if (hasNext) { float dn1 = wn1 - w1; g1 -= CC_ * (dn1 * rsqrtf(fmaf(dn1, dn1, 1e-10f))); }
        v1 = fmaf(-LR_, g1, w1);
      }

      // ---- Michelot projection, warm-started (r8/r10/r11/r13-verified numerics;
      // restored exactly after r20 showed full-support start costs +13% instrs) ----
      float a1m = val1 ? 1.f : 0.f;
      float na0 = (v0 > thp) ? 1.f : 0.f;
      float na1 = (val1 && (v1 > thp)) ? 1.f : 0.f;
      float Ssum = wred64(na0 * v0 + na1 * v1);
      float Cnt  = wred64(na0 + na1);
      if (Cnt < 0.5f) { Ssum = wred64(v0 + a1m * v1); Cnt = 100.f; }
      float theta = (Ssum - 1.f) / Cnt;
      for (int it = 0; it < 112; ++it) {
        na0 = (v0 > theta) ? 1.f : 0.f;
        na1 = (val1 && (v1 > theta)) ? 1.f : 0.f;
        float ns = wred64(na0 * v0 + na1 * v1);
        float nc = wred64(na0 + na1);
        if (nc == Cnt && ns == Ssum) break;
        if (it == 7) {  // warm-start may cycle: reset to full support (monotone)
          ns = wred64(v0 + a1m * v1);
          nc = 100.f;
        }
        Ssum = ns; Cnt = nc;
        theta = (Ssum - 1.f) / Cnt;
      }
      thp = theta;
      w0 = fmaxf(v0 - theta, 0.f);
      w1 = val1 ? fmaxf(v1 - theta, 0.f) : 0.f;

      wbuf[1 - p][j][lane] = w0;
      if (val1) wbuf[1 - p][j][64 + lane] = w1;

      // ---- cross-WG publish, DATA ONLY (boundary A): stores fly through
      // barrier-2 (raw barrier no longer drains vmcnt); fence+flag happen at
      // the start of iteration k+1.
      if (isBnd) {
        float* dst = pbuf + ((size_t)flagPub * 2 + ((k + 1) & 1)) * 100;
        sysStoreF(&dst[lane], w0);
        if (val1) sysStoreF(&dst[64 + lane], w1);
      }
    }
    BARRIER();
  }

  if (sec == 0) {
    float* o = out + (size_t)bh * 100;
    o[lane] = w0;
    if (val1) o[64 + lane] = w1;
  }
}

extern "C" void kernel_launch(void* const* d_in, const int* in_sizes, int n_in,
                              void* d_out, int out_size, void* d_ws, size_t ws_size,
                              hipStream_t stream) {
  const float* mu = (const float*)d_in[0];
  const float* L  = (const float*)d_in[1];
  const float* wp = (const float*)d_in[2];
  const float* cl = (const float*)d_in[3];
  float* pbuf  = (float*)d_ws;
  int*   flags = (int*)((char*)d_ws + PBUF_BYTES);
  hipMemsetAsync(flags, 0, FLAG_COUNT * sizeof(int), stream);
  hipLaunchKernelGGL(mpo_solver, dim3(256), dim3(768), 0, stream,
                     mu, L, wp, cl, (float*)d_out, pbuf, flags);
}